// Round 3
// baseline (505.042 us; speedup 1.0000x reference)
//
#include <hip/hip_runtime.h>
#include <stdint.h>

constexpr int NB = 32;    // batch
constexpr int NT = 2048;  // time
constexpr int NK = 1024;  // encoder hidden (K of GEMM)
constexpr int NH = 1024;  // attn hidden (N of GEMM)
constexpr int NQ = 1024;  // decoder hidden
constexpr int NTB = NT * NB;  // 65536 GEMM rows

typedef __attribute__((ext_vector_type(8))) short bf16x8;
typedef __attribute__((ext_vector_type(4))) float f32x4;

__device__ __forceinline__ short f2bf(float f) {
  union { float f; unsigned u; } c{f};
  unsigned r = (c.u + 0x7fffu + ((c.u >> 16) & 1u)) >> 16;
  return (short)r;
}

__device__ __forceinline__ void gload16(const void* g, void* l) {
  __builtin_amdgcn_global_load_lds(
      (const __attribute__((address_space(1))) unsigned int*)g,
      (__attribute__((address_space(3))) unsigned int*)l, 16, 0, 0);
}

// ---------------------------------------------------------------------------
// Kernel 0: fp32 -> bf16 bulk convert (memory-bound).  8 elems/thread/iter.
// ---------------------------------------------------------------------------
__global__ __launch_bounds__(256)
void convert_kernel(const float* __restrict__ in, short* __restrict__ out, long n) {
  long stride = (long)gridDim.x * 256 * 8;
  for (long i = ((long)blockIdx.x * 256 + threadIdx.x) * 8; i < n; i += stride) {
    float4 a = *(const float4*)(in + i);
    float4 b = *(const float4*)(in + i + 4);
    bf16x8 o;
    o[0] = f2bf(a.x); o[1] = f2bf(a.y); o[2] = f2bf(a.z); o[3] = f2bf(a.w);
    o[4] = f2bf(b.x); o[5] = f2bf(b.y); o[6] = f2bf(b.z); o[7] = f2bf(b.w);
    *(bf16x8*)(out + i) = o;
  }
}

// ---------------------------------------------------------------------------
// Kernel 1: query[b][h] = sum_q dec[b][q] * Wq[h][q]  (fp32, tiny)
// ---------------------------------------------------------------------------
__global__ __launch_bounds__(256)
void query_kernel(const float* __restrict__ dec, const float* __restrict__ Wq,
                  float* __restrict__ query) {
  int b = blockIdx.x;
  int h0 = blockIdx.y * 64;
  __shared__ float sdec[NQ];
  for (int i = threadIdx.x; i < NQ; i += 256) sdec[i] = dec[b * NQ + i];
  __syncthreads();
  int hl = threadIdx.x >> 2;
  int p  = threadIdx.x & 3;
  int h = h0 + hl;
  const float* wrow = Wq + (size_t)h * NQ;
  float s = 0.f;
  for (int k = p * 4; k < NQ; k += 16) {
    float4 w = *(const float4*)(wrow + k);
    float4 d = *(const float4*)(sdec + k);
    s += w.x * d.x + w.y * d.y + w.z * d.z + w.w * d.w;
  }
  s += __shfl_xor(s, 1);
  s += __shfl_xor(s, 2);
  if (p == 0) query[b * NH + h] = s;
}

// ---------------------------------------------------------------------------
// Kernel 2 (fast path): m97-structure bf16 GEMM + fused tanh/v-dot scores.
// 128x128 tile, BK=64, 4 waves (2x2 of 64x64), mfma_f32_16x16x32_bf16.
// LDS linear [128][64] bf16 (global_load_lds requires linear dest).
// Staging: 8x global_load_lds_dwordx4 per thread per K-step (4 A + 4 B);
// chunk = 1KB = 8 rows; wave w covers chunks {q*4+w}.
// ---------------------------------------------------------------------------
__global__ __launch_bounds__(256)
void scores_mfma_kernel(const short* __restrict__ Ebf, const short* __restrict__ Wkbf,
                        const float* __restrict__ query, const float* __restrict__ v,
                        float* __restrict__ scores) {
  const int bid = blockIdx.x;
  const int x  = bid & 7;                 // XCD
  const int ht = (bid >> 3) & 7;          // NH/128 = 8, fast index on XCD
  const int rt = x + ((bid >> 6) << 3);
  const int rowBase = rt * 128;
  const int hBase   = ht * 128;

  __shared__ short lA[128 * 64];  // 16 KB, row-major [row][k], linear
  __shared__ short lB[128 * 64];

  const int tid = threadIdx.x;
  const int lane = tid & 63;
  const int l15 = lane & 15;
  const int lhi = lane >> 4;
  const int wid = tid >> 6;
  const int wm = wid >> 1;
  const int wn = wid & 1;

  // staging: chunk c covers rows c*8..c*8+7; lane covers (lane>>3) row, (lane&7)*8 col
  const int srow0 = (lane >> 3);
  const int scol  = (lane & 7) << 3;
  const size_t ldsOff = (size_t)(wid << 9) + (lane << 3);  // shorts: chunk base + lane*8

  const short* gA = Ebf  + (size_t)(rowBase) * NK + scol;
  const short* gB = Wkbf + (size_t)(hBase)   * NK + scol;

  f32x4 acc[4][4] = {};

  for (int k0 = 0; k0 < NK; k0 += 64) {
#pragma unroll
    for (int q = 0; q < 4; ++q) {
      const int chunk = q * 4 + wid;          // 0..15
      const int row = chunk * 8 + srow0;
      gload16(gA + (size_t)row * NK + k0, &lA[(size_t)(q << 11) + ldsOff]);
      gload16(gB + (size_t)row * NK + k0, &lB[(size_t)(q << 11) + ldsOff]);
    }
    __syncthreads();  // drains vmcnt -> LDS tile visible

#pragma unroll
    for (int ks = 0; ks < 2; ++ks) {
      const int kk = ks * 32 + lhi * 8;
      bf16x8 af[4], bfr[4];
#pragma unroll
      for (int m = 0; m < 4; ++m)
        af[m] = *(const bf16x8*)&lA[(wm * 64 + m * 16 + l15) * 64 + kk];
#pragma unroll
      for (int n = 0; n < 4; ++n)
        bfr[n] = *(const bf16x8*)&lB[(wn * 64 + n * 16 + l15) * 64 + kk];
#pragma unroll
      for (int m = 0; m < 4; ++m)
#pragma unroll
        for (int n = 0; n < 4; ++n)
          acc[m][n] = __builtin_amdgcn_mfma_f32_16x16x32_bf16(af[m], bfr[n], acc[m][n], 0, 0, 0);
    }
    __syncthreads();  // compute done before next overwrite
  }

  // epilogue: tanh + v-dot, reduce over 16 col-lanes, atomic partial score
  // C/D layout: col = lane&15, row = (lane>>4)*4 + reg  [m89-verified]
#pragma unroll
  for (int m = 0; m < 4; ++m) {
#pragma unroll
    for (int reg = 0; reg < 4; ++reg) {
      int row = rowBase + wm * 64 + m * 16 + lhi * 4 + reg;
      int b = row & (NB - 1);
      float s = 0.f;
#pragma unroll
      for (int n = 0; n < 4; ++n) {
        int col = hBase + wn * 64 + n * 16 + l15;
        float c = acc[m][n][reg];
        s += tanhf(c + query[b * NH + col]) * v[col];
      }
      s += __shfl_xor(s, 1);
      s += __shfl_xor(s, 2);
      s += __shfl_xor(s, 4);
      s += __shfl_xor(s, 8);
      if (l15 == 0) atomicAdd(&scores[row], s);
    }
  }
}

// ---------------------------------------------------------------------------
// Kernel 2 (fallback, small-ws): round-2 fp32-staged version.
// ---------------------------------------------------------------------------
__global__ __launch_bounds__(256)
void scores_kernel_f32(const float* __restrict__ E, const float* __restrict__ Wk,
                       const float* __restrict__ query, const float* __restrict__ v,
                       float* __restrict__ scores) {
  const int bid = blockIdx.x;
  const int x  = bid & 7;
  const int ht = (bid >> 3) & 7;
  const int rt = x + ((bid >> 6) << 3);
  const int rowBase = rt * 128;
  const int hBase   = ht * 128;

  __shared__ short lA[128][72];
  __shared__ short lB[128][72];

  const int tid = threadIdx.x;
  const int lane = tid & 63;
  const int l15 = lane & 15;
  const int lhi = lane >> 4;
  const int wid = tid >> 6;
  const int wm = wid >> 1;
  const int wn = wid & 1;

  const int rq = tid >> 3;
  const int kq = (tid & 7) << 3;

  f32x4 acc[4][4] = {};

  for (int k0 = 0; k0 < NK; k0 += 64) {
    __syncthreads();
#pragma unroll
    for (int q = 0; q < 4; ++q) {
      int r = rq + q * 32;
      const float* pe = E  + (size_t)(rowBase + r) * NK + k0 + kq;
      const float* pw = Wk + (size_t)(hBase  + r) * NK + k0 + kq;
      float4 e0 = *(const float4*)(pe);
      float4 e1 = *(const float4*)(pe + 4);
      float4 w0 = *(const float4*)(pw);
      float4 w1 = *(const float4*)(pw + 4);
      bf16x8 se, sw;
      se[0] = f2bf(e0.x); se[1] = f2bf(e0.y); se[2] = f2bf(e0.z); se[3] = f2bf(e0.w);
      se[4] = f2bf(e1.x); se[5] = f2bf(e1.y); se[6] = f2bf(e1.z); se[7] = f2bf(e1.w);
      sw[0] = f2bf(w0.x); sw[1] = f2bf(w0.y); sw[2] = f2bf(w0.z); sw[3] = f2bf(w0.w);
      sw[4] = f2bf(w1.x); sw[5] = f2bf(w1.y); sw[6] = f2bf(w1.z); sw[7] = f2bf(w1.w);
      *(bf16x8*)&lA[r][kq] = se;
      *(bf16x8*)&lB[r][kq] = sw;
    }
    __syncthreads();

#pragma unroll
    for (int ks = 0; ks < 2; ++ks) {
      const int kk = ks * 32 + lhi * 8;
      bf16x8 af[4], bfr[4];
#pragma unroll
      for (int m = 0; m < 4; ++m)
        af[m] = *(const bf16x8*)&lA[wm * 64 + m * 16 + l15][kk];
#pragma unroll
      for (int n = 0; n < 4; ++n)
        bfr[n] = *(const bf16x8*)&lB[wn * 64 + n * 16 + l15][kk];
#pragma unroll
      for (int m = 0; m < 4; ++m)
#pragma unroll
        for (int n = 0; n < 4; ++n)
          acc[m][n] = __builtin_amdgcn_mfma_f32_16x16x32_bf16(af[m], bfr[n], acc[m][n], 0, 0, 0);
    }
  }

#pragma unroll
  for (int m = 0; m < 4; ++m) {
#pragma unroll
    for (int reg = 0; reg < 4; ++reg) {
      int row = rowBase + wm * 64 + m * 16 + lhi * 4 + reg;
      int b = row & (NB - 1);
      float s = 0.f;
#pragma unroll
      for (int n = 0; n < 4; ++n) {
        int col = hBase + wn * 64 + n * 16 + l15;
        float c = acc[m][n][reg];
        s += tanhf(c + query[b * NH + col]) * v[col];
      }
      s += __shfl_xor(s, 1);
      s += __shfl_xor(s, 2);
      s += __shfl_xor(s, 4);
      s += __shfl_xor(s, 8);
      if (l15 == 0) atomicAdd(&scores[row], s);
    }
  }
}

// ---------------------------------------------------------------------------
// Kernel 3: masked softmax over t, per b.  In-place scores -> alphas.
// ---------------------------------------------------------------------------
__global__ __launch_bounds__(256)
void softmax_kernel(const int* __restrict__ mask, float* __restrict__ alphas) {
  int b = blockIdx.x;
  int tid = threadIdx.x;
  float sv[8];
  int mv[8];
  float mx = -INFINITY;
#pragma unroll
  for (int i = 0; i < 8; ++i) {
    int t = tid + i * 256;
    sv[i] = alphas[t * NB + b];
    mv[i] = mask[t * NB + b];
    if (mv[i] != 0) mx = fmaxf(mx, sv[i]);
  }
  __shared__ float red[256];
  red[tid] = mx;
  __syncthreads();
  for (int o = 128; o > 0; o >>= 1) {
    if (tid < o) red[tid] = fmaxf(red[tid], red[tid + o]);
    __syncthreads();
  }
  mx = red[0];
  __syncthreads();
  float sum = 0.f;
#pragma unroll
  for (int i = 0; i < 8; ++i) {
    if (mv[i] != 0) { sv[i] = expf(sv[i] - mx); sum += sv[i]; }
    else sv[i] = 0.f;
  }
  red[tid] = sum;
  __syncthreads();
  for (int o = 128; o > 0; o >>= 1) {
    if (tid < o) red[tid] += red[tid + o];
    __syncthreads();
  }
  float inv = 1.f / red[0];
#pragma unroll
  for (int i = 0; i < 8; ++i) {
    int t = tid + i * 256;
    alphas[t * NB + b] = sv[i] * inv;
  }
}

// ---------------------------------------------------------------------------
// Kernel 4: context[b][k] = sum_t alphas[t][b] * E[t][b][k]  (fp32 E: precision)
// ---------------------------------------------------------------------------
__global__ __launch_bounds__(256)
void context_kernel(const float* __restrict__ E, const float* __restrict__ alphas,
                    float* __restrict__ ctx) {
  int k = blockIdx.x * 256 + threadIdx.x;
  int b = blockIdx.y;
  int t0 = blockIdx.z * 128;
  float acc = 0.f;
  for (int t = t0; t < t0 + 128; ++t) {
    float a = alphas[t * NB + b];
    acc = fmaf(a, E[((size_t)t * NB + b) * NK + k], acc);
  }
  atomicAdd(&ctx[b * NK + k], acc);
}

// ---------------------------------------------------------------------------
extern "C" void kernel_launch(void* const* d_in, const int* in_sizes, int n_in,
                              void* d_out, int out_size, void* d_ws, size_t ws_size,
                              hipStream_t stream) {
  const float* dec  = (const float*)d_in[0];
  const float* enc  = (const float*)d_in[1];
  const int*   mask = (const int*)d_in[2];
  const float* Wk   = (const float*)d_in[3];
  const float* Wq   = (const float*)d_in[4];
  const float* v    = (const float*)d_in[5];

  float* ctx    = (float*)d_out;
  float* alphas = (float*)d_out + NB * NK;

  // workspace layout
  const size_t QUERY_B = (size_t)NB * NH * sizeof(float);            // 128 KB
  const size_t WKBF_B  = (size_t)NH * NK * sizeof(short);            // 2 MB
  const size_t EBF_B   = (size_t)NTB * NK * sizeof(short);           // 128 MB
  float* query = (float*)d_ws;
  short* Wkbf  = (short*)((char*)d_ws + QUERY_B);
  short* Ebf   = (short*)((char*)d_ws + QUERY_B + WKBF_B);
  const bool fast = ws_size >= QUERY_B + WKBF_B + EBF_B;

  hipMemsetAsync(d_out, 0, (size_t)out_size * sizeof(float), stream);

  query_kernel<<<dim3(NB, NH / 64), 256, 0, stream>>>(dec, Wq, query);
  if (fast) {
    convert_kernel<<<dim3(2048), 256, 0, stream>>>(enc, Ebf, (long)NTB * NK);
    convert_kernel<<<dim3(512), 256, 0, stream>>>(Wk, Wkbf, (long)NH * NK);
    scores_mfma_kernel<<<dim3((NTB / 128) * (NH / 128)), 256, 0, stream>>>(
        Ebf, Wkbf, query, v, alphas);
  } else {
    scores_kernel_f32<<<dim3((NTB / 128) * (NH / 128)), 256, 0, stream>>>(
        enc, Wk, query, v, alphas);
  }
  softmax_kernel<<<dim3(NB), 256, 0, stream>>>(mask, alphas);
  context_kernel<<<dim3(NK / 256, NB, NT / 128), 256, 0, stream>>>(enc, alphas, ctx);
}

// Round 4
// 406.274 us; speedup vs baseline: 1.2431x; 1.2431x over previous
//
#include <hip/hip_runtime.h>
#include <stdint.h>

constexpr int NB = 32;    // batch
constexpr int NT = 2048;  // time
constexpr int NK = 1024;  // encoder hidden (K of GEMM)
constexpr int NH = 1024;  // attn hidden (N of GEMM)
constexpr int NQ = 1024;  // decoder hidden
constexpr int NTB = NT * NB;  // 65536 GEMM rows

typedef __attribute__((ext_vector_type(8))) short bf16x8;
typedef __attribute__((ext_vector_type(4))) float f32x4;

__device__ __forceinline__ short f2bf(float f) {
  union { float f; unsigned u; } c{f};
  unsigned r = (c.u + 0x7fffu + ((c.u >> 16) & 1u)) >> 16;
  return (short)r;
}

// tanh via exp2-hw: (e-1)/(e+1), e=exp(2x), clamped.  ~6 VALU ops, err ~1e-6.
__device__ __forceinline__ float fast_tanh(float x) {
  float e = __expf(fminf(fmaxf(x + x, -30.f), 30.f));
  return (e - 1.f) * __builtin_amdgcn_rcpf(e + 1.f);
}

__device__ __forceinline__ void gload16(const void* g, void* l) {
  __builtin_amdgcn_global_load_lds(
      (const __attribute__((address_space(1))) unsigned int*)g,
      (__attribute__((address_space(3))) unsigned int*)l, 16, 0, 0);
}

// ---------------------------------------------------------------------------
// Kernel 0: fp32 -> bf16 convert WITH baked LDS swizzle.
// Row width fixed at 1024. Within each 64-col K-slice (8 chunks of 8 elems),
// stored chunk c holds source chunk (c ^ (row&7)).  The GEMM stages rows
// verbatim (linear gload_lds) and un-swizzles on ds_read -> conflict-free.
// ---------------------------------------------------------------------------
__global__ __launch_bounds__(256)
void convert_swz_kernel(const float* __restrict__ in, short* __restrict__ out,
                        long nchunks) {
  long stride = (long)gridDim.x * 256;
  for (long i = (long)blockIdx.x * 256 + threadIdx.x; i < nchunks; i += stride) {
    long r = i >> 7;            // 128 chunks per 1024-wide row
    int c = (int)(i & 127);
    int src = (c & ~7) | ((c & 7) ^ ((int)r & 7));
    const float* p = in + (r << 10) + (src << 3);
    float4 a = *(const float4*)p;
    float4 b = *(const float4*)(p + 4);
    bf16x8 o;
    o[0] = f2bf(a.x); o[1] = f2bf(a.y); o[2] = f2bf(a.z); o[3] = f2bf(a.w);
    o[4] = f2bf(b.x); o[5] = f2bf(b.y); o[6] = f2bf(b.z); o[7] = f2bf(b.w);
    *(bf16x8*)(out + (i << 3)) = o;
  }
}

// ---------------------------------------------------------------------------
// Kernel 1: query[b][h] = sum_q dec[b][q] * Wq[h][q]  (fp32, tiny)
// ---------------------------------------------------------------------------
__global__ __launch_bounds__(256)
void query_kernel(const float* __restrict__ dec, const float* __restrict__ Wq,
                  float* __restrict__ query) {
  int b = blockIdx.x;
  int h0 = blockIdx.y * 64;
  __shared__ float sdec[NQ];
  for (int i = threadIdx.x; i < NQ; i += 256) sdec[i] = dec[b * NQ + i];
  __syncthreads();
  int hl = threadIdx.x >> 2;
  int p  = threadIdx.x & 3;
  int h = h0 + hl;
  const float* wrow = Wq + (size_t)h * NQ;
  float s = 0.f;
  for (int k = p * 4; k < NQ; k += 16) {
    float4 w = *(const float4*)(wrow + k);
    float4 d = *(const float4*)(sdec + k);
    s += w.x * d.x + w.y * d.y + w.z * d.z + w.w * d.w;
  }
  s += __shfl_xor(s, 1);
  s += __shfl_xor(s, 2);
  if (p == 0) query[b * NH + h] = s;
}

// ---------------------------------------------------------------------------
// Kernel 2: double-buffered bf16-MFMA GEMM + fused fast-tanh/v-dot scores.
// 128x128 tile, BK=64, 4 waves (2x2 of 64x64), mfma_f32_16x16x32_bf16.
// Prefetch: STAGE(next) issued BEFORE compute(cur); one __syncthreads()
// (= vmcnt(0)+barrier) per K-step.  LDS 2x(16+16) KB = 64 KB -> 2 blocks/CU.
// ds_read un-swizzles chunk^(row&7): 16 lanes cover 32 banks 2-way (free).
// ---------------------------------------------------------------------------
__global__ __launch_bounds__(256)
void scores_mfma_kernel(const short* __restrict__ Ebf, const short* __restrict__ Wkbf,
                        const float* __restrict__ query, const float* __restrict__ v,
                        float* __restrict__ scores) {
  const int bid = blockIdx.x;
  const int x  = bid & 7;                 // XCD
  const int ht = (bid >> 3) & 7;          // NH/128 = 8, fast index on XCD
  const int rt = x + ((bid >> 6) << 3);
  const int rowBase = rt * 128;
  const int hBase   = ht * 128;

  __shared__ short lA[2][128 * 64];  // 2 x 16 KB
  __shared__ short lB[2][128 * 64];

  const int tid = threadIdx.x;
  const int lane = tid & 63;
  const int l15 = lane & 15;
  const int lhi = lane >> 4;
  const int wid = tid >> 6;
  const int wm = wid >> 1;
  const int wn = wid & 1;

  const int srow0 = (lane >> 3);
  const int scol  = (lane & 7) << 3;
  const int ldsOffS = (wid << 9) + (lane << 3);  // shorts

  const short* gA = Ebf  + (size_t)(rowBase) * NK + scol;
  const short* gB = Wkbf + (size_t)(hBase)   * NK + scol;

  f32x4 acc[4][4] = {};

  auto STAGE = [&](int buf, int k0) {
#pragma unroll
    for (int q = 0; q < 4; ++q) {
      const int row = (q * 4 + wid) * 8 + srow0;
      gload16(gA + (size_t)row * NK + k0, &lA[buf][(q << 11) + ldsOffS]);
      gload16(gB + (size_t)row * NK + k0, &lB[buf][(q << 11) + ldsOffS]);
    }
  };

  STAGE(0, 0);
  __syncthreads();

  for (int t = 0; t < 16; ++t) {
    const int cur = t & 1;
    if (t < 15) STAGE(cur ^ 1, (t + 1) * 64);
#pragma unroll
    for (int ks = 0; ks < 2; ++ks) {
      bf16x8 af[4], bfr[4];
#pragma unroll
      for (int m = 0; m < 4; ++m) {
        int row = wm * 64 + m * 16 + l15;
        int ch = ((ks * 4 + lhi) ^ (row & 7)) << 3;
        af[m] = *(const bf16x8*)&lA[cur][row * 64 + ch];
      }
#pragma unroll
      for (int n = 0; n < 4; ++n) {
        int row = wn * 64 + n * 16 + l15;
        int ch = ((ks * 4 + lhi) ^ (row & 7)) << 3;
        bfr[n] = *(const bf16x8*)&lB[cur][row * 64 + ch];
      }
#pragma unroll
      for (int m = 0; m < 4; ++m)
#pragma unroll
        for (int n = 0; n < 4; ++n)
          acc[m][n] = __builtin_amdgcn_mfma_f32_16x16x32_bf16(af[m], bfr[n], acc[m][n], 0, 0, 0);
    }
    __syncthreads();  // vmcnt(0)+barrier: next buffer staged, cur buffer free
  }

  // epilogue: fast-tanh + v-dot, reduce over 16 col-lanes, atomic partial
  // C/D layout: col = lane&15, row = (lane>>4)*4 + reg  [m89-verified]
#pragma unroll
  for (int m = 0; m < 4; ++m) {
#pragma unroll
    for (int reg = 0; reg < 4; ++reg) {
      int row = rowBase + wm * 64 + m * 16 + lhi * 4 + reg;
      int b = row & (NB - 1);
      float s = 0.f;
#pragma unroll
      for (int n = 0; n < 4; ++n) {
        int col = hBase + wn * 64 + n * 16 + l15;
        float c = acc[m][n][reg];
        s += fast_tanh(c + query[b * NH + col]) * v[col];
      }
      s += __shfl_xor(s, 1);
      s += __shfl_xor(s, 2);
      s += __shfl_xor(s, 4);
      s += __shfl_xor(s, 8);
      if (l15 == 0) atomicAdd(&scores[row], s);
    }
  }
}

// ---------------------------------------------------------------------------
// Kernel 2 (fallback, small-ws): fp32 reg-staged version (round-2, correct).
// ---------------------------------------------------------------------------
__global__ __launch_bounds__(256)
void scores_kernel_f32(const float* __restrict__ E, const float* __restrict__ Wk,
                       const float* __restrict__ query, const float* __restrict__ v,
                       float* __restrict__ scores) {
  const int bid = blockIdx.x;
  const int x  = bid & 7;
  const int ht = (bid >> 3) & 7;
  const int rt = x + ((bid >> 6) << 3);
  const int rowBase = rt * 128;
  const int hBase   = ht * 128;

  __shared__ short lA[128][72];
  __shared__ short lB[128][72];

  const int tid = threadIdx.x;
  const int lane = tid & 63;
  const int l15 = lane & 15;
  const int lhi = lane >> 4;
  const int wid = tid >> 6;
  const int wm = wid >> 1;
  const int wn = wid & 1;

  const int rq = tid >> 3;
  const int kq = (tid & 7) << 3;

  f32x4 acc[4][4] = {};

  for (int k0 = 0; k0 < NK; k0 += 64) {
    __syncthreads();
#pragma unroll
    for (int q = 0; q < 4; ++q) {
      int r = rq + q * 32;
      const float* pe = E  + (size_t)(rowBase + r) * NK + k0 + kq;
      const float* pw = Wk + (size_t)(hBase  + r) * NK + k0 + kq;
      float4 e0 = *(const float4*)(pe);
      float4 e1 = *(const float4*)(pe + 4);
      float4 w0 = *(const float4*)(pw);
      float4 w1 = *(const float4*)(pw + 4);
      bf16x8 se, sw;
      se[0] = f2bf(e0.x); se[1] = f2bf(e0.y); se[2] = f2bf(e0.z); se[3] = f2bf(e0.w);
      se[4] = f2bf(e1.x); se[5] = f2bf(e1.y); se[6] = f2bf(e1.z); se[7] = f2bf(e1.w);
      sw[0] = f2bf(w0.x); sw[1] = f2bf(w0.y); sw[2] = f2bf(w0.z); sw[3] = f2bf(w0.w);
      sw[4] = f2bf(w1.x); sw[5] = f2bf(w1.y); sw[6] = f2bf(w1.z); sw[7] = f2bf(w1.w);
      *(bf16x8*)&lA[r][kq] = se;
      *(bf16x8*)&lB[r][kq] = sw;
    }
    __syncthreads();

#pragma unroll
    for (int ks = 0; ks < 2; ++ks) {
      const int kk = ks * 32 + lhi * 8;
      bf16x8 af[4], bfr[4];
#pragma unroll
      for (int m = 0; m < 4; ++m)
        af[m] = *(const bf16x8*)&lA[wm * 64 + m * 16 + l15][kk];
#pragma unroll
      for (int n = 0; n < 4; ++n)
        bfr[n] = *(const bf16x8*)&lB[wn * 64 + n * 16 + l15][kk];
#pragma unroll
      for (int m = 0; m < 4; ++m)
#pragma unroll
        for (int n = 0; n < 4; ++n)
          acc[m][n] = __builtin_amdgcn_mfma_f32_16x16x32_bf16(af[m], bfr[n], acc[m][n], 0, 0, 0);
    }
  }

#pragma unroll
  for (int m = 0; m < 4; ++m) {
#pragma unroll
    for (int reg = 0; reg < 4; ++reg) {
      int row = rowBase + wm * 64 + m * 16 + lhi * 4 + reg;
      int b = row & (NB - 1);
      float s = 0.f;
#pragma unroll
      for (int n = 0; n < 4; ++n) {
        int col = hBase + wn * 64 + n * 16 + l15;
        float c = acc[m][n][reg];
        s += fast_tanh(c + query[b * NH + col]) * v[col];
      }
      s += __shfl_xor(s, 1);
      s += __shfl_xor(s, 2);
      s += __shfl_xor(s, 4);
      s += __shfl_xor(s, 8);
      if (l15 == 0) atomicAdd(&scores[row], s);
    }
  }
}

// ---------------------------------------------------------------------------
// Kernel 3: masked softmax over t, per b.  In-place scores -> alphas.
// ---------------------------------------------------------------------------
__global__ __launch_bounds__(256)
void softmax_kernel(const int* __restrict__ mask, float* __restrict__ alphas) {
  int b = blockIdx.x;
  int tid = threadIdx.x;
  float sv[8];
  int mv[8];
  float mx = -INFINITY;
#pragma unroll
  for (int i = 0; i < 8; ++i) {
    int t = tid + i * 256;
    sv[i] = alphas[t * NB + b];
    mv[i] = mask[t * NB + b];
    if (mv[i] != 0) mx = fmaxf(mx, sv[i]);
  }
  __shared__ float red[256];
  red[tid] = mx;
  __syncthreads();
  for (int o = 128; o > 0; o >>= 1) {
    if (tid < o) red[tid] = fmaxf(red[tid], red[tid + o]);
    __syncthreads();
  }
  mx = red[0];
  __syncthreads();
  float sum = 0.f;
#pragma unroll
  for (int i = 0; i < 8; ++i) {
    if (mv[i] != 0) { sv[i] = expf(sv[i] - mx); sum += sv[i]; }
    else sv[i] = 0.f;
  }
  red[tid] = sum;
  __syncthreads();
  for (int o = 128; o > 0; o >>= 1) {
    if (tid < o) red[tid] += red[tid + o];
    __syncthreads();
  }
  float inv = 1.f / red[0];
#pragma unroll
  for (int i = 0; i < 8; ++i) {
    int t = tid + i * 256;
    alphas[t * NB + b] = sv[i] * inv;
  }
}

// ---------------------------------------------------------------------------
// Kernel 4: context[b][k] = sum_t alphas[t][b] * E[t][b][k]  (fp32 E)
// ---------------------------------------------------------------------------
__global__ __launch_bounds__(256)
void context_kernel(const float* __restrict__ E, const float* __restrict__ alphas,
                    float* __restrict__ ctx) {
  int k = blockIdx.x * 256 + threadIdx.x;
  int b = blockIdx.y;
  int t0 = blockIdx.z * 128;
  float acc = 0.f;
  for (int t = t0; t < t0 + 128; ++t) {
    float a = alphas[t * NB + b];
    acc = fmaf(a, E[((size_t)t * NB + b) * NK + k], acc);
  }
  atomicAdd(&ctx[b * NK + k], acc);
}

// ---------------------------------------------------------------------------
extern "C" void kernel_launch(void* const* d_in, const int* in_sizes, int n_in,
                              void* d_out, int out_size, void* d_ws, size_t ws_size,
                              hipStream_t stream) {
  const float* dec  = (const float*)d_in[0];
  const float* enc  = (const float*)d_in[1];
  const int*   mask = (const int*)d_in[2];
  const float* Wk   = (const float*)d_in[3];
  const float* Wq   = (const float*)d_in[4];
  const float* v    = (const float*)d_in[5];

  float* ctx    = (float*)d_out;
  float* alphas = (float*)d_out + NB * NK;

  const size_t QUERY_B = (size_t)NB * NH * sizeof(float);            // 128 KB
  const size_t WKBF_B  = (size_t)NH * NK * sizeof(short);            // 2 MB
  const size_t EBF_B   = (size_t)NTB * NK * sizeof(short);           // 128 MB
  float* query = (float*)d_ws;
  short* Wkbf  = (short*)((char*)d_ws + QUERY_B);
  short* Ebf   = (short*)((char*)d_ws + QUERY_B + WKBF_B);
  const bool fast = ws_size >= QUERY_B + WKBF_B + EBF_B;

  hipMemsetAsync(d_out, 0, (size_t)out_size * sizeof(float), stream);

  query_kernel<<<dim3(NB, NH / 64), 256, 0, stream>>>(dec, Wq, query);
  if (fast) {
    convert_swz_kernel<<<dim3(2048), 256, 0, stream>>>(enc, Ebf, (long)NTB * NK / 8);
    convert_swz_kernel<<<dim3(512), 256, 0, stream>>>(Wk, Wkbf, (long)NH * NK / 8);
    scores_mfma_kernel<<<dim3((NTB / 128) * (NH / 128)), 256, 0, stream>>>(
        Ebf, Wkbf, query, v, alphas);
  } else {
    scores_kernel_f32<<<dim3((NTB / 128) * (NH / 128)), 256, 0, stream>>>(
        enc, Wk, query, v, alphas);
  }
  softmax_kernel<<<dim3(NB), 256, 0, stream>>>(mask, alphas);
  context_kernel<<<dim3(NK / 256, NB, NT / 128), 256, 0, stream>>>(enc, alphas, ctx);
}

// Round 6
// 349.361 us; speedup vs baseline: 1.4456x; 1.1629x over previous
//
#include <hip/hip_runtime.h>
#include <stdint.h>

constexpr int NB = 32;    // batch
constexpr int NT = 2048;  // time
constexpr int NK = 1024;  // encoder hidden (K of GEMM)
constexpr int NH = 1024;  // attn hidden (N of GEMM)
constexpr int NQ = 1024;  // decoder hidden
constexpr int NTB = NT * NB;  // 65536 GEMM rows

typedef __attribute__((ext_vector_type(8))) short bf16x8;
typedef __attribute__((ext_vector_type(4))) float f32x4;

__device__ __forceinline__ short f2bf(float f) {
  union { float f; unsigned u; } c{f};
  unsigned r = (c.u + 0x7fffu + ((c.u >> 16) & 1u)) >> 16;
  return (short)r;
}

// tanh via hw exp: (e-1)/(e+1), e=exp(2x), clamped.  ~6 VALU ops.
__device__ __forceinline__ float fast_tanh(float x) {
  float e = __expf(fminf(fmaxf(x + x, -30.f), 30.f));
  return (e - 1.f) * __builtin_amdgcn_rcpf(e + 1.f);
}

__device__ __forceinline__ void gload16(const void* g, void* l) {
  __builtin_amdgcn_global_load_lds(
      (const __attribute__((address_space(1))) unsigned int*)g,
      (__attribute__((address_space(3))) unsigned int*)l, 16, 0, 0);
}

// ---------------------------------------------------------------------------
// Kernel 0: fp32 -> bf16 convert WITH baked LDS bank-swizzle.
// Within each 64-col K-slice (8 chunks of 8 elems), stored chunk c holds
// source chunk (c ^ (row&7)).  GEMM stages rows verbatim (linear gload_lds,
// LINEAR source) and un-swizzles on ds_read -> conflict-free (r4: conflicts=0).
// The involution appears ONCE on the write path (here) and once on read.
// ---------------------------------------------------------------------------
__global__ __launch_bounds__(256)
void convert_swz_kernel(const float* __restrict__ in, short* __restrict__ out,
                        long nchunks) {
  long stride = (long)gridDim.x * 256;
  for (long i = (long)blockIdx.x * 256 + threadIdx.x; i < nchunks; i += stride) {
    long r = i >> 7;            // 128 chunks per 1024-wide row
    int c = (int)(i & 127);
    int src = (c & ~7) | ((c & 7) ^ ((int)r & 7));
    const float* p = in + (r << 10) + (src << 3);
    float4 a = *(const float4*)p;
    float4 b = *(const float4*)(p + 4);
    bf16x8 o;
    o[0] = f2bf(a.x); o[1] = f2bf(a.y); o[2] = f2bf(a.z); o[3] = f2bf(a.w);
    o[4] = f2bf(b.x); o[5] = f2bf(b.y); o[6] = f2bf(b.z); o[7] = f2bf(b.w);
    *(bf16x8*)(out + (i << 3)) = o;
  }
}

// ---------------------------------------------------------------------------
// Kernel 1: query[b][h] = sum_q dec[b][q] * Wq[h][q]  (fp32, tiny)
// ---------------------------------------------------------------------------
__global__ __launch_bounds__(256)
void query_kernel(const float* __restrict__ dec, const float* __restrict__ Wq,
                  float* __restrict__ query) {
  int b = blockIdx.x;
  int h0 = blockIdx.y * 64;
  __shared__ float sdec[NQ];
  for (int i = threadIdx.x; i < NQ; i += 256) sdec[i] = dec[b * NQ + i];
  __syncthreads();
  int hl = threadIdx.x >> 2;
  int p  = threadIdx.x & 3;
  int h = h0 + hl;
  const float* wrow = Wq + (size_t)h * NQ;
  float s = 0.f;
  for (int k = p * 4; k < NQ; k += 16) {
    float4 w = *(const float4*)(wrow + k);
    float4 d = *(const float4*)(sdec + k);
    s += w.x * d.x + w.y * d.y + w.z * d.z + w.w * d.w;
  }
  s += __shfl_xor(s, 1);
  s += __shfl_xor(s, 2);
  if (p == 0) query[b * NH + h] = s;
}

// ---------------------------------------------------------------------------
// Kernel 2: ring-3 counted-vmcnt bf16-MFMA GEMM + fused tanh/v-dot scores.
// BM=256, BN=128, BK=64, 512 threads = 8 waves (4M x 2N), 64x64 out/wave.
// LDS ring of 3 slots: A 3x32KB + B 3x16KB = 144KB dynamic, 1 block/CU.
// Compute tile t from slot t%3 while staging tile t+2 into slot (t+2)%3
// (= slot of t-1, whose reads drained at the boundary).  Boundary:
// s_waitcnt lgkmcnt(0) vmcnt(6) + s_barrier -- tile t+1's 6 loads stay in
// flight across the barrier (never drain to 0 in the main loop).
// STAGE source is LINEAR (data pre-swizzled by convert); ds_read un-swizzles.
// ---------------------------------------------------------------------------
__global__ __launch_bounds__(512, 2)
void scores_mfma_kernel(const short* __restrict__ Ebf, const short* __restrict__ Wkbf,
                        const float* __restrict__ query, const float* __restrict__ v,
                        float* __restrict__ scores) {
  extern __shared__ short smem[];
  short* lA = smem;                    // 3 * 256*64 shorts
  short* lB = smem + 3 * 256 * 64;     // 3 * 128*64 shorts

  const int bid = blockIdx.x;
  const int x  = bid & 7;                  // XCD
  const int ht = (bid >> 3) & 7;           // NH/128 = 8, fast on XCD
  const int rt = ((bid >> 6) << 3) + x;    // 0..255
  const int rowBase = rt * 256;
  const int hBase   = ht * 128;

  const int tid  = threadIdx.x;
  const int lane = tid & 63;
  const int l15  = lane & 15;
  const int lhi  = lane >> 4;
  const int wid  = tid >> 6;      // 0..7
  const int wm   = wid >> 1;      // 0..3 : 64-row band
  const int wn   = wid & 1;       // 0..1 : 64-col band

  const int srow = tid >> 3;      // 0..63 staging row within round
  const int sc   = lane & 7;      // staging chunk (LDS dest = lane*16B contiguous)

  f32x4 acc[4][4] = {};

  auto STAGE = [&](int slot, int t) {
    const int k0 = t << 6;
    short* la = lA + slot * (256 * 64);
    short* lb = lB + slot * (128 * 64);
    const int src = k0 + (sc << 3);   // LINEAR: swizzle already baked in Ebf/Wkbf
#pragma unroll
    for (int r = 0; r < 4; ++r) {
      const int row = r * 64 + srow;
      gload16(Ebf + (size_t)(rowBase + row) * NK + src, la + row * 64 + (sc << 3));
    }
#pragma unroll
    for (int r = 0; r < 2; ++r) {
      const int row = r * 64 + srow;
      gload16(Wkbf + (size_t)(hBase + row) * NK + src, lb + row * 64 + (sc << 3));
    }
  };

  STAGE(0, 0);
  STAGE(1, 1);

  for (int t = 0; t < 16; ++t) {
    const int slot = t % 3;
    // boundary: own ds_reads drained (lgkm); own tile-t loads landed (vmcnt
    // leaves only tile t+1's 6 newest in flight); barrier makes EVERY wave's
    // tile-t loads visible before any wave reads slot t.
    if (t < 15) {
      asm volatile("s_waitcnt lgkmcnt(0) vmcnt(6)" ::: "memory");
    } else {
      asm volatile("s_waitcnt lgkmcnt(0) vmcnt(0)" ::: "memory");
    }
    __builtin_amdgcn_s_barrier();

    const short* la = lA + slot * (256 * 64);
    const short* lb = lB + slot * (128 * 64);

    bf16x8 af[4][2], bg[4][2];
#pragma unroll
    for (int m = 0; m < 4; ++m) {
      const int row = wm * 64 + m * 16 + l15;
#pragma unroll
      for (int ks = 0; ks < 2; ++ks) {
        const int ch = ((ks * 4 + lhi) ^ (row & 7)) << 3;
        af[m][ks] = *(const bf16x8*)(la + row * 64 + ch);
      }
    }
    if (t < 14) STAGE((t + 2) % 3, t + 2);   // writes slot (t-1)%3: drained above
#pragma unroll
    for (int n = 0; n < 4; ++n) {
      const int row = wn * 64 + n * 16 + l15;
#pragma unroll
      for (int ks = 0; ks < 2; ++ks) {
        const int ch = ((ks * 4 + lhi) ^ (row & 7)) << 3;
        bg[n][ks] = *(const bf16x8*)(lb + row * 64 + ch);
      }
    }
#pragma unroll
    for (int ks = 0; ks < 2; ++ks)
#pragma unroll
      for (int m = 0; m < 4; ++m)
#pragma unroll
        for (int n = 0; n < 4; ++n)
          acc[m][n] = __builtin_amdgcn_mfma_f32_16x16x32_bf16(af[m][ks], bg[n][ks], acc[m][n], 0, 0, 0);
  }

  // epilogue: fast-tanh + v-dot, shfl-reduce over 16 col-lanes, atomic partial
  // C/D layout: col = lane&15, row = (lane>>4)*4 + reg  [m89-verified]
#pragma unroll
  for (int m = 0; m < 4; ++m) {
#pragma unroll
    for (int reg = 0; reg < 4; ++reg) {
      int row = rowBase + wm * 64 + m * 16 + lhi * 4 + reg;
      int b = row & (NB - 1);
      float s = 0.f;
#pragma unroll
      for (int n = 0; n < 4; ++n) {
        int col = hBase + wn * 64 + n * 16 + l15;
        float c = acc[m][n][reg];
        s += fast_tanh(c + query[b * NH + col]) * v[col];
      }
      s += __shfl_xor(s, 1);
      s += __shfl_xor(s, 2);
      s += __shfl_xor(s, 4);
      s += __shfl_xor(s, 8);
      if (l15 == 0) atomicAdd(&scores[row], s);
    }
  }
}

// ---------------------------------------------------------------------------
// Kernel 2 (fallback, small-ws): fp32 reg-staged version (round-2, correct).
// ---------------------------------------------------------------------------
__global__ __launch_bounds__(256)
void scores_kernel_f32(const float* __restrict__ E, const float* __restrict__ Wk,
                       const float* __restrict__ query, const float* __restrict__ v,
                       float* __restrict__ scores) {
  const int bid = blockIdx.x;
  const int x  = bid & 7;
  const int ht = (bid >> 3) & 7;
  const int rt = x + ((bid >> 6) << 3);
  const int rowBase = rt * 128;
  const int hBase   = ht * 128;

  __shared__ short lA[128][72];
  __shared__ short lB[128][72];

  const int tid = threadIdx.x;
  const int lane = tid & 63;
  const int l15 = lane & 15;
  const int lhi = lane >> 4;
  const int wid = tid >> 6;
  const int wm = wid >> 1;
  const int wn = wid & 1;

  const int rq = tid >> 3;
  const int kq = (tid & 7) << 3;

  f32x4 acc[4][4] = {};

  for (int k0 = 0; k0 < NK; k0 += 64) {
    __syncthreads();
#pragma unroll
    for (int q = 0; q < 4; ++q) {
      int r = rq + q * 32;
      const float* pe = E  + (size_t)(rowBase + r) * NK + k0 + kq;
      const float* pw = Wk + (size_t)(hBase  + r) * NK + k0 + kq;
      float4 e0 = *(const float4*)(pe);
      float4 e1 = *(const float4*)(pe + 4);
      float4 w0 = *(const float4*)(pw);
      float4 w1 = *(const float4*)(pw + 4);
      bf16x8 se, sw;
      se[0] = f2bf(e0.x); se[1] = f2bf(e0.y); se[2] = f2bf(e0.z); se[3] = f2bf(e0.w);
      se[4] = f2bf(e1.x); se[5] = f2bf(e1.y); se[6] = f2bf(e1.z); se[7] = f2bf(e1.w);
      sw[0] = f2bf(w0.x); sw[1] = f2bf(w0.y); sw[2] = f2bf(w0.z); sw[3] = f2bf(w0.w);
      sw[4] = f2bf(w1.x); sw[5] = f2bf(w1.y); sw[6] = f2bf(w1.z); sw[7] = f2bf(w1.w);
      *(bf16x8*)&lA[r][kq] = se;
      *(bf16x8*)&lB[r][kq] = sw;
    }
    __syncthreads();

#pragma unroll
    for (int ks = 0; ks < 2; ++ks) {
      const int kk = ks * 32 + lhi * 8;
      bf16x8 af[4], bfr[4];
#pragma unroll
      for (int m = 0; m < 4; ++m)
        af[m] = *(const bf16x8*)&lA[wm * 64 + m * 16 + l15][kk];
#pragma unroll
      for (int n = 0; n < 4; ++n)
        bfr[n] = *(const bf16x8*)&lB[wn * 64 + n * 16 + l15][kk];
#pragma unroll
      for (int m = 0; m < 4; ++m)
#pragma unroll
        for (int n = 0; n < 4; ++n)
          acc[m][n] = __builtin_amdgcn_mfma_f32_16x16x32_bf16(af[m], bfr[n], acc[m][n], 0, 0, 0);
    }
  }

#pragma unroll
  for (int m = 0; m < 4; ++m) {
#pragma unroll
    for (int reg = 0; reg < 4; ++reg) {
      int row = rowBase + wm * 64 + m * 16 + lhi * 4 + reg;
      int b = row & (NB - 1);
      float s = 0.f;
#pragma unroll
      for (int n = 0; n < 4; ++n) {
        int col = hBase + wn * 64 + n * 16 + l15;
        float c = acc[m][n][reg];
        s += fast_tanh(c + query[b * NH + col]) * v[col];
      }
      s += __shfl_xor(s, 1);
      s += __shfl_xor(s, 2);
      s += __shfl_xor(s, 4);
      s += __shfl_xor(s, 8);
      if (l15 == 0) atomicAdd(&scores[row], s);
    }
  }
}

// ---------------------------------------------------------------------------
// Kernel 3: masked softmax over t, per b.  In-place scores -> alphas.
// ---------------------------------------------------------------------------
__global__ __launch_bounds__(256)
void softmax_kernel(const int* __restrict__ mask, float* __restrict__ alphas) {
  int b = blockIdx.x;
  int tid = threadIdx.x;
  float sv[8];
  int mv[8];
  float mx = -INFINITY;
#pragma unroll
  for (int i = 0; i < 8; ++i) {
    int t = tid + i * 256;
    sv[i] = alphas[t * NB + b];
    mv[i] = mask[t * NB + b];
    if (mv[i] != 0) mx = fmaxf(mx, sv[i]);
  }
  __shared__ float red[256];
  red[tid] = mx;
  __syncthreads();
  for (int o = 128; o > 0; o >>= 1) {
    if (tid < o) red[tid] = fmaxf(red[tid], red[tid + o]);
    __syncthreads();
  }
  mx = red[0];
  __syncthreads();
  float sum = 0.f;
#pragma unroll
  for (int i = 0; i < 8; ++i) {
    if (mv[i] != 0) { sv[i] = expf(sv[i] - mx); sum += sv[i]; }
    else sv[i] = 0.f;
  }
  red[tid] = sum;
  __syncthreads();
  for (int o = 128; o > 0; o >>= 1) {
    if (tid < o) red[tid] += red[tid + o];
    __syncthreads();
  }
  float inv = 1.f / red[0];
#pragma unroll
  for (int i = 0; i < 8; ++i) {
    int t = tid + i * 256;
    alphas[t * NB + b] = sv[i] * inv;
  }
}

// ---------------------------------------------------------------------------
// Kernel 4: context[b][k] = sum_t alphas[t][b] * E[t][b][k]  (fp32 E)
// ---------------------------------------------------------------------------
__global__ __launch_bounds__(256)
void context_kernel(const float* __restrict__ E, const float* __restrict__ alphas,
                    float* __restrict__ ctx) {
  int k = blockIdx.x * 256 + threadIdx.x;
  int b = blockIdx.y;
  int t0 = blockIdx.z * 128;
  float acc = 0.f;
  for (int t = t0; t < t0 + 128; ++t) {
    float a = alphas[t * NB + b];
    acc = fmaf(a, E[((size_t)t * NB + b) * NK + k], acc);
  }
  atomicAdd(&ctx[b * NK + k], acc);
}

// ---------------------------------------------------------------------------
extern "C" void kernel_launch(void* const* d_in, const int* in_sizes, int n_in,
                              void* d_out, int out_size, void* d_ws, size_t ws_size,
                              hipStream_t stream) {
  const float* dec  = (const float*)d_in[0];
  const float* enc  = (const float*)d_in[1];
  const int*   mask = (const int*)d_in[2];
  const float* Wk   = (const float*)d_in[3];
  const float* Wq   = (const float*)d_in[4];
  const float* v    = (const float*)d_in[5];

  float* ctx    = (float*)d_out;
  float* alphas = (float*)d_out + NB * NK;

  const size_t QUERY_B = (size_t)NB * NH * sizeof(float);            // 128 KB
  const size_t WKBF_B  = (size_t)NH * NK * sizeof(short);            // 2 MB
  const size_t EBF_B   = (size_t)NTB * NK * sizeof(short);           // 128 MB
  float* query = (float*)d_ws;
  short* Wkbf  = (short*)((char*)d_ws + QUERY_B);
  short* Ebf   = (short*)((char*)d_ws + QUERY_B + WKBF_B);
  const bool fast = ws_size >= QUERY_B + WKBF_B + EBF_B;

  hipMemsetAsync(d_out, 0, (size_t)out_size * sizeof(float), stream);

  query_kernel<<<dim3(NB, NH / 64), 256, 0, stream>>>(dec, Wq, query);
  if (fast) {
    convert_swz_kernel<<<dim3(2048), 256, 0, stream>>>(enc, Ebf, (long)NTB * NK / 8);
    convert_swz_kernel<<<dim3(512), 256, 0, stream>>>(Wk, Wkbf, (long)NH * NK / 8);
    const int SMEM = (3 * 256 * 64 + 3 * 128 * 64) * (int)sizeof(short);  // 144 KB
    hipFuncSetAttribute((const void*)scores_mfma_kernel,
                        hipFuncAttributeMaxDynamicSharedMemorySize, SMEM);
    scores_mfma_kernel<<<dim3((NTB / 256) * (NH / 128)), dim3(512), SMEM, stream>>>(
        Ebf, Wkbf, query, v, alphas);
  } else {
    scores_kernel_f32<<<dim3((NTB / 128) * (NH / 128)), 256, 0, stream>>>(
        enc, Wk, query, v, alphas);
  }
  softmax_kernel<<<dim3(NB), 256, 0, stream>>>(mask, alphas);
  context_kernel<<<dim3(NK / 256, NB, NT / 128), 256, 0, stream>>>(enc, alphas, ctx);
}